// Round 5
// baseline (273.265 us; speedup 1.0000x reference)
//
#include <hip/hip_runtime.h>
#include <hip/hip_bf16.h>
#include <math.h>

// Shapes (fixed): B=2048, D=1024, H=1024, Z=256, E=64
// out = concat(h1[B,H], c1[B,H], hhat1[B,Z], chat1[B,Z]) fp32
//
// Pipeline (4 launches):
//  1. k_prep       : pack hcat bf16 + build combined Bt + small transposes
//  2. k_gemm_main  : C[2048][5120] = hcat @ [pad|W ; hW]  (512 thr, BK=64, swizzled)
//  3. k_gemm_zcell : hyper cell (hg->hhat1/chat1, bf16 into LDS) + z GEMM
//  4. k_dmod_lstm  : barrier-free direct-fragment d-einsum + modulation + cell

typedef __attribute__((ext_vector_type(8))) short bf16x8;
typedef __attribute__((ext_vector_type(4))) float f32x4;
typedef unsigned short u16;

__device__ __forceinline__ u16 f2b(float f) {
  union { float f; unsigned u; } v; v.f = f;
  unsigned r = v.u + 0x7fffu + ((v.u >> 16) & 1u);   // RNE
  return (u16)(r >> 16);
}
__device__ __forceinline__ float b2f(u16 b) {
  union { unsigned u; float f; } v; v.u = ((unsigned)b) << 16; return v.f;
}
__device__ __forceinline__ float sigm(float x) { return 1.f / (1.f + __expf(-x)); }

#define GLL16(gsrc, ldst)                                                      \
  __builtin_amdgcn_global_load_lds(                                            \
      (const __attribute__((address_space(1))) void*)(gsrc),                   \
      (__attribute__((address_space(3))) void*)(ldst), 16, 0, 0)

// ---------------- merged prep ----------------
// blocks [0,4608)            : pack hcat = [hhat0|h0|x] -> bf16 [2048][2304]
// blocks [4608, 4608+5760)   : build Bt [5120][2304] (skip n<4096,k<256 pad)
// blocks [10368, 10368+480)  : zwT (3x 256x256) + dwT (12x 64x1024 -> 1024x64)
__global__ void k_prep(const float* __restrict__ hhat0, const float* __restrict__ h0,
                       const float* __restrict__ x, const float* __restrict__ weight,
                       const float* __restrict__ hweight,
                       const float* __restrict__ zw_h, const float* __restrict__ zw_x,
                       const float* __restrict__ zw_b, const float* __restrict__ dw_h,
                       const float* __restrict__ dw_x, const float* __restrict__ dw_b,
                       u16* __restrict__ hcatb, u16* __restrict__ bt,
                       u16* __restrict__ zwT, u16* __restrict__ dwT) {
  __shared__ float tile[32][66];
  int bid = blockIdx.x;
  const int t = threadIdx.x;
  if (bid < 4608) {
    int i = bid * 256 + t;                 // over 2048*576 float4s
    int b = i / 576, c4 = i % 576;
    const float* src;
    if (c4 < 64)       src = hhat0 + (long)b * 256 + c4 * 4;
    else if (c4 < 320) src = h0 + (long)b * 1024 + (c4 - 64) * 4;
    else               src = x + (long)b * 1024 + (c4 - 320) * 4;
    float4 v = *(const float4*)src;
    ushort4 o = {f2b(v.x), f2b(v.y), f2b(v.z), f2b(v.w)};
    *(ushort4*)&hcatb[(long)b * 2304 + c4 * 4] = o;
    return;
  }
  bid -= 4608;
  if (bid < 5760) {                        // build Bt
    const int n0 = (bid % 160) * 32, k0 = (bid / 160) * 64;
    if (n0 < 4096 && k0 < 256) return;
    const float* src; int C, sc0, sr0;
    if (n0 >= 4096) { src = hweight; C = 1024; sc0 = n0 - 4096; sr0 = k0; }
    else            { src = weight;  C = 4096; sc0 = n0;        sr0 = k0 - 256; }
    #pragma unroll
    for (int p = 0; p < 8; ++p) {
      int c = t & 31, r = (t >> 5) + 8 * p;
      tile[c][r] = src[(long)(sr0 + r) * C + sc0 + c];
    }
    __syncthreads();
    #pragma unroll
    for (int p = 0; p < 2; ++p) {
      int kc = t & 15, cl = (t >> 4) + 16 * p;
      ushort4 o = {f2b(tile[cl][4 * kc]), f2b(tile[cl][4 * kc + 1]),
                   f2b(tile[cl][4 * kc + 2]), f2b(tile[cl][4 * kc + 3])};
      *(ushort4*)&bt[(long)(n0 + cl) * 2304 + k0 + 4 * kc] = o;
    }
    return;
  }
  bid -= 5760;                             // small transposes
  const int zi = bid >> 5, bx = bid & 31;
  const float* src; u16* dst; int R, C;
  if (zi < 3) {
    src = (zi == 0) ? zw_h : (zi == 1) ? zw_x : zw_b;
    dst = zwT + (long)zi * 65536; R = 256; C = 256;
  } else {
    int s = zi - 3, tt = s >> 2, g = s & 3;
    src = ((tt == 0) ? dw_h : (tt == 1) ? dw_x : dw_b) + (long)g * 65536;
    dst = dwT + (long)s * 65536; R = 64; C = 1024;
  }
  const int nct = C / 32;
  const int c0 = (bx % nct) * 32, r0 = (bx / nct) * 64;
  #pragma unroll
  for (int p = 0; p < 8; ++p) {
    int c = t & 31, r = (t >> 5) + 8 * p;
    tile[c][r] = src[(long)(r0 + r) * C + c0 + c];
  }
  __syncthreads();
  #pragma unroll
  for (int p = 0; p < 2; ++p) {
    int kc = t & 15, cl = (t >> 4) + 16 * p;
    ushort4 o = {f2b(tile[cl][4 * kc]), f2b(tile[cl][4 * kc + 1]),
                 f2b(tile[cl][4 * kc + 2]), f2b(tile[cl][4 * kc + 3])};
    *(ushort4*)&dst[(long)(c0 + cl) * R + r0 + 4 * kc] = o;
  }
}

// ---------------- main GEMM: 512 threads, 128x128 tile, BK=64, swizzled LDS ----------------
__global__ __launch_bounds__(512, 4)
void k_gemm_main(const u16* __restrict__ A, const u16* __restrict__ Bt,
                 float* __restrict__ hgbuf, u16* __restrict__ grawb) {
  constexpr int K = 2304;
  __shared__ __align__(16) u16 sA[128 * 64];   // 16 KB
  __shared__ __align__(16) u16 sB[128 * 64];
  const int m0 = blockIdx.y * 128, n0 = blockIdx.x * 128;
  const int kstart = (n0 < 4096) ? 256 : 0;
  const int tid = threadIdx.x, wave = tid >> 6, lane = tid & 63;
  const int quad = lane >> 4, lrow = lane & 15;
  const int wm = (wave >> 2) * 64, wn = (wave & 3) * 32;

  // staging: 2 rounds/operand; 128B rows, 8 chunks; phys p holds logical q=(p-row)&7
  const int l0 = tid * 16, l1 = 8192 + tid * 16;
  const int r0 = l0 >> 7, r1 = l1 >> 7;
  const int q0 = (((l0 >> 4) & 7) - r0) & 7;
  const int q1 = (((l1 >> 4) & 7) - r1) & 7;
  const long aoff0 = ((long)(m0 + r0) * K + q0 * 8) * 2;
  const long aoff1 = ((long)(m0 + r1) * K + q1 * 8) * 2;
  const long boff0 = ((long)(n0 + r0) * K + q0 * 8) * 2;
  const long boff1 = ((long)(n0 + r1) * K + q1 * 8) * 2;

  const f32x4 vz = {0.f, 0.f, 0.f, 0.f};
  f32x4 acc[4][2];
  #pragma unroll
  for (int i = 0; i < 4; ++i)
    #pragma unroll
    for (int j = 0; j < 2; ++j) acc[i][j] = vz;

  for (int k0 = kstart; k0 < K; k0 += 64) {
    const long kb = (long)k0 * 2;
    GLL16((const char*)A + aoff0 + kb, (char*)sA + wave * 1024);
    GLL16((const char*)A + aoff1 + kb, (char*)sA + 8192 + wave * 1024);
    GLL16((const char*)Bt + boff0 + kb, (char*)sB + wave * 1024);
    GLL16((const char*)Bt + boff1 + kb, (char*)sB + 8192 + wave * 1024);
    __syncthreads();
    #pragma unroll
    for (int kk = 0; kk < 2; ++kk) {
      bf16x8 af[4], bf[2];
      #pragma unroll
      for (int i = 0; i < 4; ++i) {
        int row = wm + i * 16 + lrow;
        int ph = (kk * 4 + quad + row) & 7;
        af[i] = *(const bf16x8*)((const char*)sA + row * 128 + ph * 16);
      }
      #pragma unroll
      for (int j = 0; j < 2; ++j) {
        int row = wn + j * 16 + lrow;
        int ph = (kk * 4 + quad + row) & 7;
        bf[j] = *(const bf16x8*)((const char*)sB + row * 128 + ph * 16);
      }
      #pragma unroll
      for (int i = 0; i < 4; ++i)
        #pragma unroll
        for (int j = 0; j < 2; ++j)
          acc[i][j] = __builtin_amdgcn_mfma_f32_16x16x32_bf16(af[i], bf[j], acc[i][j], 0, 0, 0);
    }
    __syncthreads();
  }
  #pragma unroll
  for (int i = 0; i < 4; ++i) {
    #pragma unroll
    for (int j = 0; j < 2; ++j) {
      #pragma unroll
      for (int r = 0; r < 4; ++r) {
        int row = m0 + wm + i * 16 + quad * 4 + r;
        int col = n0 + wn + j * 16 + lrow;
        float v = acc[i][j][r];
        if (col < 4096) grawb[(long)row * 4096 + col] = f2b(v);
        else            hgbuf[(long)row * 1024 + (col - 4096)] = v;
      }
    }
  }
}

// ---------------- fused hyper cell + z GEMM ----------------
// Block: 64 rows x 128 z-cols. Phase 1: compute hhat1 (bf16) into LDS (swizzled)
// + write hhat1/chat1 outputs (bx==0 only). Phase 2: z = hhat1 @ zwT + zbias.
__global__ __launch_bounds__(256, 2)
void k_gemm_zcell(const float* __restrict__ hg, const float* __restrict__ hbias,
                  const float* __restrict__ chat0, const u16* __restrict__ zwT,
                  const float* __restrict__ zbh, const float* __restrict__ zbx,
                  float* __restrict__ chat1, float* __restrict__ hhat1,
                  u16* __restrict__ zbout) {
  __shared__ __align__(16) u16 sH[64 * 256];   // 32 KB: row=512B=32 chunks, phys=(lc+row)&31
  __shared__ __align__(16) u16 sB[128 * 32];   // 8 KB
  const int m0 = blockIdx.y * 64, n0 = blockIdx.x * 128;
  const int tid = threadIdx.x;

  // ---- cell phase: thread t owns col zc=t across all 64 rows ----
  {
    const int zc = tid;
    const float hb_i = hbias[zc], hb_g = hbias[256 + zc];
    const float hb_f = hbias[512 + zc], hb_o = hbias[768 + zc];
    #pragma unroll 4
    for (int row = 0; row < 64; ++row) {
      const float* r = hg + (long)(m0 + row) * 1024;
      float ih = r[zc] + hb_i, gh = r[256 + zc] + hb_g;
      float fh = r[512 + zc] + hb_f, oh = r[768 + zc] + hb_o;
      long cidx = (long)(m0 + row) * 256 + zc;
      float c = sigm(fh) * chat0[cidx] + sigm(ih) * tanhf(gh);
      float h = sigm(oh) * tanhf(c);
      if (n0 == 0) { chat1[cidx] = c; hhat1[cidx] = h; }
      int ph = ((zc >> 3) + row) & 31;
      sH[row * 256 + ph * 8 + (zc & 7)] = f2b(h);
    }
  }
  __syncthreads();

  // ---- GEMM phase: 4 waves, wave tile 32x64 ----
  const int wave = tid >> 6, lane = tid & 63;
  const int quad = lane >> 4, lrow = lane & 15;
  const int wm = (wave >> 1) * 32, wn = (wave & 1) * 64;
  const f32x4 vz = {0.f, 0.f, 0.f, 0.f};
  f32x4 acc[2][4];
  #pragma unroll
  for (int i = 0; i < 2; ++i)
    #pragma unroll
    for (int j = 0; j < 4; ++j) acc[i][j] = vz;

  for (int k0 = 0; k0 < 256; k0 += 32) {
    #pragma unroll
    for (int c = 0; c < 2; ++c) {
      int l = c * 4096 + tid * 16;
      int row = l >> 6;
      int q = (((l >> 4) & 3) - (row >> 1)) & 3;
      const char* g = (const char*)zwT + ((long)(n0 + row) * 256 + k0 + q * 8) * 2;
      GLL16(g, (char*)sB + c * 4096 + wave * 1024);
    }
    __syncthreads();
    bf16x8 af[2], bf[4];
    #pragma unroll
    for (int i = 0; i < 2; ++i) {
      int row = wm + i * 16 + lrow;
      int ph = ((k0 >> 3) + quad + row) & 31;
      af[i] = *(const bf16x8*)((const char*)sH + row * 512 + ph * 16);
    }
    #pragma unroll
    for (int j = 0; j < 4; ++j) {
      int row = wn + j * 16 + lrow;
      int ph = (quad + (row >> 1)) & 3;
      bf[j] = *(const bf16x8*)((const char*)sB + row * 64 + ph * 16);
    }
    #pragma unroll
    for (int i = 0; i < 2; ++i)
      #pragma unroll
      for (int j = 0; j < 4; ++j)
        acc[i][j] = __builtin_amdgcn_mfma_f32_16x16x32_bf16(af[i], bf[j], acc[i][j], 0, 0, 0);
    __syncthreads();
  }
  #pragma unroll
  for (int i = 0; i < 2; ++i) {
    #pragma unroll
    for (int j = 0; j < 4; ++j) {
      #pragma unroll
      for (int r = 0; r < 4; ++r) {
        int row = m0 + wm + i * 16 + quad * 4 + r;
        int col = n0 + wn + j * 16 + lrow;
        float v = acc[i][j][r] + ((col < 256) ? zbh[col] : (col < 512) ? zbx[col - 256] : 0.f);
        zbout[(long)row * 768 + col] = f2b(v);
      }
    }
  }
}

// ---------------- barrier-free dmod + main cell ----------------
// Wave tile 32 rows x 32 cols; fragments loaded DIRECTLY from global (L2-hot z/dwT).
// No LDS, no __syncthreads.
__global__ __launch_bounds__(256, 2)
void k_dmod_lstm(const u16* __restrict__ z, const u16* __restrict__ dwT,
                 const u16* __restrict__ grawb, const float* __restrict__ bias,
                 const float* __restrict__ c0, float* __restrict__ h1,
                 float* __restrict__ c1) {
  const int m0 = blockIdx.y * 64, hc0 = blockIdx.x * 64;
  const int tid = threadIdx.x, wave = tid >> 6, lane = tid & 63;
  const int quad = lane >> 4, lrow = lane & 15;
  const int rm = m0 + (wave >> 1) * 32;
  const int cn = hc0 + (wave & 1) * 32;
  const f32x4 vz4 = {0.f, 0.f, 0.f, 0.f};

  f32x4 pcar[2][2];   // progressive carry: sigm(i) -> sigm(i)*tanh(g)
  f32x4 ccar[2][2];   // c1

  #pragma unroll
  for (int g = 0; g < 4; ++g) {
    f32x4 aH[2][2], aX[2][2], aB[2][2];
    #pragma unroll
    for (int i = 0; i < 2; ++i)
      #pragma unroll
      for (int j = 0; j < 2; ++j) { aH[i][j] = vz4; aX[i][j] = vz4; aB[i][j] = vz4; }

    #pragma unroll
    for (int t = 0; t < 3; ++t) {
      bf16x8 za[2][2], wb[2][2];
      #pragma unroll
      for (int kk = 0; kk < 2; ++kk) {
        #pragma unroll
        for (int i = 0; i < 2; ++i)
          za[kk][i] = *(const bf16x8*)(z + (long)(rm + i * 16 + lrow) * 768 +
                                       t * 256 + g * 64 + kk * 32 + quad * 8);
        #pragma unroll
        for (int j = 0; j < 2; ++j)
          wb[kk][j] = *(const bf16x8*)(dwT + (long)((t * 4 + g) * 1024 + cn + j * 16 + lrow) * 64 +
                                       kk * 32 + quad * 8);
      }
      #pragma unroll
      for (int kk = 0; kk < 2; ++kk)
        #pragma unroll
        for (int i = 0; i < 2; ++i)
          #pragma unroll
          for (int j = 0; j < 2; ++j) {
            if (t == 0)
              aH[i][j] = __builtin_amdgcn_mfma_f32_16x16x32_bf16(za[kk][i], wb[kk][j], aH[i][j], 0, 0, 0);
            else if (t == 1)
              aX[i][j] = __builtin_amdgcn_mfma_f32_16x16x32_bf16(za[kk][i], wb[kk][j], aX[i][j], 0, 0, 0);
            else
              aB[i][j] = __builtin_amdgcn_mfma_f32_16x16x32_bf16(za[kk][i], wb[kk][j], aB[i][j], 0, 0, 0);
          }
    }
    #pragma unroll
    for (int i = 0; i < 2; ++i) {
      #pragma unroll
      for (int j = 0; j < 2; ++j) {
        #pragma unroll
        for (int r = 0; r < 4; ++r) {
          int row = rm + i * 16 + quad * 4 + r;
          int col = cn + j * 16 + lrow;
          float gr = b2f(grawb[(long)row * 4096 + g * 1024 + col]);
          float v = gr * aH[i][j][r] * aX[i][j][r] + aB[i][j][r] + bias[g * 1024 + col];
          long idx = (long)row * 1024 + col;
          if (g == 0) pcar[i][j][r] = sigm(v);
          else if (g == 1) pcar[i][j][r] *= tanhf(v);
          else if (g == 2) {
            float cc = sigm(v) * c0[idx] + pcar[i][j][r];
            ccar[i][j][r] = cc;
            c1[idx] = cc;
          } else {
            h1[idx] = sigm(v) * tanhf(ccar[i][j][r]);
          }
        }
      }
    }
  }
}

// ---------------- launch ----------------

extern "C" void kernel_launch(void* const* d_in, const int* in_sizes, int n_in,
                              void* d_out, int out_size, void* d_ws, size_t ws_size,
                              hipStream_t stream) {
  const float* x      = (const float*)d_in[0];
  const float* h0     = (const float*)d_in[1];
  const float* c0     = (const float*)d_in[2];
  const float* hhat0  = (const float*)d_in[3];
  const float* chat0  = (const float*)d_in[4];
  const float* hweight= (const float*)d_in[5];
  const float* hbias  = (const float*)d_in[6];
  const float* zw_h   = (const float*)d_in[7];
  const float* zw_x   = (const float*)d_in[8];
  const float* zw_b   = (const float*)d_in[9];
  const float* zb_h   = (const float*)d_in[10];
  const float* zb_x   = (const float*)d_in[11];
  const float* dw_h   = (const float*)d_in[12];
  const float* dw_x   = (const float*)d_in[13];
  const float* dw_b   = (const float*)d_in[14];
  const float* weight = (const float*)d_in[15];
  const float* bias   = (const float*)d_in[16];
  float* out = (float*)d_out;

  char* w = (char*)d_ws;
  auto take = [&](size_t bytes) { char* p = w; w += (bytes + 255) & ~(size_t)255; return p; };
  u16*   hcatb  = (u16*)take(2048ull * 2304 * 2);
  u16*   btc    = (u16*)take(5120ull * 2304 * 2);
  u16*   zwT    = (u16*)take(768ull * 256 * 2);
  u16*   dwT    = (u16*)take(12ull * 1024 * 64 * 2);
  u16*   grawb  = (u16*)take(2048ull * 4096 * 2);
  float* hgbuf  = (float*)take(2048ull * 1024 * 4);
  u16*   zb16   = (u16*)take(2048ull * 768 * 2);

  float* h1_o    = out;
  float* c1_o    = out + 2048 * 1024;
  float* hhat1_o = out + 2 * 2048 * 1024;
  float* chat1_o = out + 2 * 2048 * 1024 + 2048 * 256;

  k_prep<<<4608 + 5760 + 480, 256, 0, stream>>>(
      hhat0, h0, x, weight, hweight, zw_h, zw_x, zw_b, dw_h, dw_x, dw_b,
      hcatb, btc, zwT, dwT);

  k_gemm_main<<<dim3(40, 16), 512, 0, stream>>>(hcatb, btc, hgbuf, grawb);

  k_gemm_zcell<<<dim3(6, 32), 256, 0, stream>>>(hgbuf, hbias, chat0, zwT, zb_h, zb_x,
                                                chat1_o, hhat1_o, zb16);

  k_dmod_lstm<<<dim3(16, 32), 256, 0, stream>>>(zb16, dwT, grawb, bias, c0, h1_o, c1_o);
}

// Round 6
// 249.419 us; speedup vs baseline: 1.0956x; 1.0956x over previous
//
#include <hip/hip_runtime.h>
#include <hip/hip_bf16.h>
#include <math.h>

// Shapes (fixed): B=2048, D=1024, H=1024, Z=256, E=64
// out = concat(h1[B,H], c1[B,H], hhat1[B,Z], chat1[B,Z]) fp32
//
// Pipeline (5 launches):
//  1. k_prep      : pack hcat bf16 + build combined Bt + small transposes
//  2. k_gemm_main : C[2048][5120] = hcat @ [pad|W ; hW]  (512 thr, BK=64, swizzled)
//  3. k_hyper_act : hyper LSTM cell -> hhat1/chat1 (+ bf16 hhat1)
//  4. k_gemm_z    : z = hhat1 @ [zw_h|zw_x|zw_b] + zbias (bf16 out)
//  5. k_dmod_lstm : barrier-free d-einsum + modulation + cell (g-loop NOT unrolled)

typedef __attribute__((ext_vector_type(8))) short bf16x8;
typedef __attribute__((ext_vector_type(4))) float f32x4;
typedef unsigned short u16;

__device__ __forceinline__ u16 f2b(float f) {
  union { float f; unsigned u; } v; v.f = f;
  unsigned r = v.u + 0x7fffu + ((v.u >> 16) & 1u);   // RNE
  return (u16)(r >> 16);
}
__device__ __forceinline__ float b2f(u16 b) {
  union { unsigned u; float f; } v; v.u = ((unsigned)b) << 16; return v.f;
}
__device__ __forceinline__ float sigm(float x) { return 1.f / (1.f + __expf(-x)); }

#define GLL16(gsrc, ldst)                                                      \
  __builtin_amdgcn_global_load_lds(                                            \
      (const __attribute__((address_space(1))) void*)(gsrc),                   \
      (__attribute__((address_space(3))) void*)(ldst), 16, 0, 0)

// ---------------- merged prep ----------------
__global__ void k_prep(const float* __restrict__ hhat0, const float* __restrict__ h0,
                       const float* __restrict__ x, const float* __restrict__ weight,
                       const float* __restrict__ hweight,
                       const float* __restrict__ zw_h, const float* __restrict__ zw_x,
                       const float* __restrict__ zw_b, const float* __restrict__ dw_h,
                       const float* __restrict__ dw_x, const float* __restrict__ dw_b,
                       u16* __restrict__ hcatb, u16* __restrict__ bt,
                       u16* __restrict__ zwT, u16* __restrict__ dwT) {
  __shared__ float tile[32][66];
  int bid = blockIdx.x;
  const int t = threadIdx.x;
  if (bid < 4608) {
    int i = bid * 256 + t;                 // over 2048*576 float4s
    int b = i / 576, c4 = i % 576;
    const float* src;
    if (c4 < 64)       src = hhat0 + (long)b * 256 + c4 * 4;
    else if (c4 < 320) src = h0 + (long)b * 1024 + (c4 - 64) * 4;
    else               src = x + (long)b * 1024 + (c4 - 320) * 4;
    float4 v = *(const float4*)src;
    ushort4 o = {f2b(v.x), f2b(v.y), f2b(v.z), f2b(v.w)};
    *(ushort4*)&hcatb[(long)b * 2304 + c4 * 4] = o;
    return;
  }
  bid -= 4608;
  if (bid < 5760) {                        // build Bt
    const int n0 = (bid % 160) * 32, k0 = (bid / 160) * 64;
    if (n0 < 4096 && k0 < 256) return;
    const float* src; int C, sc0, sr0;
    if (n0 >= 4096) { src = hweight; C = 1024; sc0 = n0 - 4096; sr0 = k0; }
    else            { src = weight;  C = 4096; sc0 = n0;        sr0 = k0 - 256; }
    #pragma unroll
    for (int p = 0; p < 8; ++p) {
      int c = t & 31, r = (t >> 5) + 8 * p;
      tile[c][r] = src[(long)(sr0 + r) * C + sc0 + c];
    }
    __syncthreads();
    #pragma unroll
    for (int p = 0; p < 2; ++p) {
      int kc = t & 15, cl = (t >> 4) + 16 * p;
      ushort4 o = {f2b(tile[cl][4 * kc]), f2b(tile[cl][4 * kc + 1]),
                   f2b(tile[cl][4 * kc + 2]), f2b(tile[cl][4 * kc + 3])};
      *(ushort4*)&bt[(long)(n0 + cl) * 2304 + k0 + 4 * kc] = o;
    }
    return;
  }
  bid -= 5760;                             // small transposes
  const int zi = bid >> 5, bx = bid & 31;
  const float* src; u16* dst; int R, C;
  if (zi < 3) {
    src = (zi == 0) ? zw_h : (zi == 1) ? zw_x : zw_b;
    dst = zwT + (long)zi * 65536; R = 256; C = 256;
  } else {
    int s = zi - 3, tt = s >> 2, g = s & 3;
    src = ((tt == 0) ? dw_h : (tt == 1) ? dw_x : dw_b) + (long)g * 65536;
    dst = dwT + (long)s * 65536; R = 64; C = 1024;
  }
  const int nct = C / 32;
  const int c0 = (bx % nct) * 32, r0 = (bx / nct) * 64;
  #pragma unroll
  for (int p = 0; p < 8; ++p) {
    int c = t & 31, r = (t >> 5) + 8 * p;
    tile[c][r] = src[(long)(r0 + r) * C + c0 + c];
  }
  __syncthreads();
  #pragma unroll
  for (int p = 0; p < 2; ++p) {
    int kc = t & 15, cl = (t >> 4) + 16 * p;
    ushort4 o = {f2b(tile[cl][4 * kc]), f2b(tile[cl][4 * kc + 1]),
                 f2b(tile[cl][4 * kc + 2]), f2b(tile[cl][4 * kc + 3])};
    *(ushort4*)&dst[(long)(c0 + cl) * R + r0 + 4 * kc] = o;
  }
}

// ---------------- main GEMM: 512 threads, 128x128 tile, BK=64, swizzled LDS ----------------
__global__ __launch_bounds__(512, 4)
void k_gemm_main(const u16* __restrict__ A, const u16* __restrict__ Bt,
                 float* __restrict__ hgbuf, u16* __restrict__ grawb) {
  constexpr int K = 2304;
  __shared__ __align__(16) u16 sA[128 * 64];   // 16 KB
  __shared__ __align__(16) u16 sB[128 * 64];
  const int m0 = blockIdx.y * 128, n0 = blockIdx.x * 128;
  const int kstart = (n0 < 4096) ? 256 : 0;
  const int tid = threadIdx.x, wave = tid >> 6, lane = tid & 63;
  const int quad = lane >> 4, lrow = lane & 15;
  const int wm = (wave >> 2) * 64, wn = (wave & 3) * 32;

  const int l0 = tid * 16, l1 = 8192 + tid * 16;
  const int r0 = l0 >> 7, r1 = l1 >> 7;
  const int q0 = (((l0 >> 4) & 7) - r0) & 7;
  const int q1 = (((l1 >> 4) & 7) - r1) & 7;
  const long aoff0 = ((long)(m0 + r0) * K + q0 * 8) * 2;
  const long aoff1 = ((long)(m0 + r1) * K + q1 * 8) * 2;
  const long boff0 = ((long)(n0 + r0) * K + q0 * 8) * 2;
  const long boff1 = ((long)(n0 + r1) * K + q1 * 8) * 2;

  const f32x4 vz = {0.f, 0.f, 0.f, 0.f};
  f32x4 acc[4][2];
  #pragma unroll
  for (int i = 0; i < 4; ++i)
    #pragma unroll
    for (int j = 0; j < 2; ++j) acc[i][j] = vz;

  for (int k0 = kstart; k0 < K; k0 += 64) {
    const long kb = (long)k0 * 2;
    GLL16((const char*)A + aoff0 + kb, (char*)sA + wave * 1024);
    GLL16((const char*)A + aoff1 + kb, (char*)sA + 8192 + wave * 1024);
    GLL16((const char*)Bt + boff0 + kb, (char*)sB + wave * 1024);
    GLL16((const char*)Bt + boff1 + kb, (char*)sB + 8192 + wave * 1024);
    __syncthreads();
    #pragma unroll
    for (int kk = 0; kk < 2; ++kk) {
      bf16x8 af[4], bf[2];
      #pragma unroll
      for (int i = 0; i < 4; ++i) {
        int row = wm + i * 16 + lrow;
        int ph = (kk * 4 + quad + row) & 7;
        af[i] = *(const bf16x8*)((const char*)sA + row * 128 + ph * 16);
      }
      #pragma unroll
      for (int j = 0; j < 2; ++j) {
        int row = wn + j * 16 + lrow;
        int ph = (kk * 4 + quad + row) & 7;
        bf[j] = *(const bf16x8*)((const char*)sB + row * 128 + ph * 16);
      }
      #pragma unroll
      for (int i = 0; i < 4; ++i)
        #pragma unroll
        for (int j = 0; j < 2; ++j)
          acc[i][j] = __builtin_amdgcn_mfma_f32_16x16x32_bf16(af[i], bf[j], acc[i][j], 0, 0, 0);
    }
    __syncthreads();
  }
  #pragma unroll
  for (int i = 0; i < 4; ++i) {
    #pragma unroll
    for (int j = 0; j < 2; ++j) {
      #pragma unroll
      for (int r = 0; r < 4; ++r) {
        int row = m0 + wm + i * 16 + quad * 4 + r;
        int col = n0 + wn + j * 16 + lrow;
        float v = acc[i][j][r];
        if (col < 4096) grawb[(long)row * 4096 + col] = f2b(v);
        else            hgbuf[(long)row * 1024 + (col - 4096)] = v;
      }
    }
  }
}

// ---------------- hyper LSTM cell ----------------
__global__ void k_hyper_act(const float* __restrict__ hgbuf, const float* __restrict__ hbias,
                            const float* __restrict__ chat0,
                            float* __restrict__ chat1, float* __restrict__ hhat1,
                            u16* __restrict__ hhat1b) {
  int idx = blockIdx.x * 256 + threadIdx.x;        // over 2048*256
  int b = idx >> 8, zc = idx & 255;
  const float* row = hgbuf + (long)b * 1024;
  float ih = row[zc] + hbias[zc];
  float gh = row[256 + zc] + hbias[256 + zc];
  float fh = row[512 + zc] + hbias[512 + zc];
  float oh = row[768 + zc] + hbias[768 + zc];
  float c = sigm(fh) * chat0[idx] + sigm(ih) * tanhf(gh);
  float h = sigm(oh) * tanhf(c);
  chat1[idx] = c;
  hhat1[idx] = h;
  hhat1b[idx] = f2b(h);
}

// ---------------- z GEMM: 256 threads, 64x128 tile ----------------
__global__ __launch_bounds__(256, 2)
void k_gemm_z(const u16* __restrict__ A, const u16* __restrict__ Bt,
              const float* __restrict__ zbh, const float* __restrict__ zbx,
              u16* __restrict__ zbout) {
  constexpr int K = 256, BK = 32;
  __shared__ __align__(16) u16 sA[64 * BK];
  __shared__ __align__(16) u16 sB[128 * BK];
  const int m0 = blockIdx.y * 64, n0 = blockIdx.x * 128;
  const int tid = threadIdx.x, wave = tid >> 6, lane = tid & 63;
  const int quad = lane >> 4, lrow = lane & 15;
  const int wm = (wave >> 1) * 32, wn = (wave & 1) * 64;

  const int sl = tid * 16;
  const int arow = sl >> 6;
  const int aq = (((sl & 63) >> 4) - (arow >> 1)) & 3;
  const long aoff = ((long)(m0 + arow) * K) * 2 + aq * 16;

  const f32x4 vz = {0.f, 0.f, 0.f, 0.f};
  f32x4 acc[2][4];
  #pragma unroll
  for (int i = 0; i < 2; ++i)
    #pragma unroll
    for (int j = 0; j < 4; ++j) acc[i][j] = vz;

  for (int k0 = 0; k0 < K; k0 += BK) {
    GLL16((const char*)A + aoff + (long)k0 * 2, (char*)sA + wave * 1024);
    #pragma unroll
    for (int c = 0; c < 2; ++c) {
      int l = c * 4096 + sl;
      int row = l >> 6;
      int q = (((l & 63) >> 4) - (row >> 1)) & 3;
      const char* g = (const char*)Bt + ((long)(n0 + row) * K + k0) * 2 + q * 16;
      GLL16(g, (char*)sB + c * 4096 + wave * 1024);
    }
    __syncthreads();
    bf16x8 af[2], bf[4];
    #pragma unroll
    for (int i = 0; i < 2; ++i) {
      int row = wm + i * 16 + lrow;
      af[i] = *(const bf16x8*)((const char*)sA + row * 64 + (((quad + (row >> 1)) & 3) << 4));
    }
    #pragma unroll
    for (int j = 0; j < 4; ++j) {
      int row = wn + j * 16 + lrow;
      bf[j] = *(const bf16x8*)((const char*)sB + row * 64 + (((quad + (row >> 1)) & 3) << 4));
    }
    #pragma unroll
    for (int i = 0; i < 2; ++i)
      #pragma unroll
      for (int j = 0; j < 4; ++j)
        acc[i][j] = __builtin_amdgcn_mfma_f32_16x16x32_bf16(af[i], bf[j], acc[i][j], 0, 0, 0);
    __syncthreads();
  }
  #pragma unroll
  for (int i = 0; i < 2; ++i) {
    #pragma unroll
    for (int j = 0; j < 4; ++j) {
      #pragma unroll
      for (int r = 0; r < 4; ++r) {
        int row = m0 + wm + i * 16 + quad * 4 + r;
        int col = n0 + wn + j * 16 + lrow;
        float v = acc[i][j][r] + ((col < 256) ? zbh[col] : (col < 512) ? zbx[col - 256] : 0.f);
        zbout[(long)row * 768 + col] = f2b(v);
      }
    }
  }
}

// ---------------- barrier-free dmod + main cell ----------------
// 32 rows x 64 cols per block, grid (16,64) = 1024 blocks (4/CU). Wave tile
// 16 rows x 32 cols. Gate loop NOT unrolled (caps live registers to one gate).
__global__ __launch_bounds__(256, 4)
void k_dmod_lstm(const u16* __restrict__ z, const u16* __restrict__ dwT,
                 const u16* __restrict__ grawb, const float* __restrict__ bias,
                 const float* __restrict__ c0, float* __restrict__ h1,
                 float* __restrict__ c1) {
  const int m0 = blockIdx.y * 32, hc0 = blockIdx.x * 64;
  const int tid = threadIdx.x, wave = tid >> 6, lane = tid & 63;
  const int quad = lane >> 4, lrow = lane & 15;
  const int rm = m0 + (wave >> 1) * 16;
  const int cn = hc0 + (wave & 1) * 32;
  const f32x4 vz4 = {0.f, 0.f, 0.f, 0.f};

  f32x4 pcar[2];   // progressive carry: sigm(i) -> sigm(i)*tanh(g)
  f32x4 ccar[2];   // c1

  #pragma unroll 1
  for (int g = 0; g < 4; ++g) {
    f32x4 aH[2], aX[2], aB[2];
    #pragma unroll
    for (int j = 0; j < 2; ++j) { aH[j] = vz4; aX[j] = vz4; aB[j] = vz4; }

    #pragma unroll
    for (int t = 0; t < 3; ++t) {
      bf16x8 za[2], wb[2][2];
      #pragma unroll
      for (int kk = 0; kk < 2; ++kk) {
        za[kk] = *(const bf16x8*)(z + (long)(rm + lrow) * 768 +
                                  t * 256 + g * 64 + kk * 32 + quad * 8);
        #pragma unroll
        for (int j = 0; j < 2; ++j)
          wb[kk][j] = *(const bf16x8*)(dwT + (long)((t * 4 + g) * 1024 + cn + j * 16 + lrow) * 64 +
                                       kk * 32 + quad * 8);
      }
      #pragma unroll
      for (int kk = 0; kk < 2; ++kk)
        #pragma unroll
        for (int j = 0; j < 2; ++j) {
          if (t == 0)
            aH[j] = __builtin_amdgcn_mfma_f32_16x16x32_bf16(za[kk], wb[kk][j], aH[j], 0, 0, 0);
          else if (t == 1)
            aX[j] = __builtin_amdgcn_mfma_f32_16x16x32_bf16(za[kk], wb[kk][j], aX[j], 0, 0, 0);
          else
            aB[j] = __builtin_amdgcn_mfma_f32_16x16x32_bf16(za[kk], wb[kk][j], aB[j], 0, 0, 0);
        }
    }
    #pragma unroll
    for (int j = 0; j < 2; ++j) {
      #pragma unroll
      for (int r = 0; r < 4; ++r) {
        int row = rm + quad * 4 + r;
        int col = cn + j * 16 + lrow;
        float gr = b2f(grawb[(long)row * 4096 + g * 1024 + col]);
        float v = gr * aH[j][r] * aX[j][r] + aB[j][r] + bias[g * 1024 + col];
        long idx = (long)row * 1024 + col;
        if (g == 0) pcar[j][r] = sigm(v);
        else if (g == 1) pcar[j][r] *= tanhf(v);
        else if (g == 2) {
          float cc = sigm(v) * c0[idx] + pcar[j][r];
          ccar[j][r] = cc;
          c1[idx] = cc;
        } else {
          h1[idx] = sigm(v) * tanhf(ccar[j][r]);
        }
      }
    }
  }
}

// ---------------- launch ----------------

extern "C" void kernel_launch(void* const* d_in, const int* in_sizes, int n_in,
                              void* d_out, int out_size, void* d_ws, size_t ws_size,
                              hipStream_t stream) {
  const float* x      = (const float*)d_in[0];
  const float* h0     = (const float*)d_in[1];
  const float* c0     = (const float*)d_in[2];
  const float* hhat0  = (const float*)d_in[3];
  const float* chat0  = (const float*)d_in[4];
  const float* hweight= (const float*)d_in[5];
  const float* hbias  = (const float*)d_in[6];
  const float* zw_h   = (const float*)d_in[7];
  const float* zw_x   = (const float*)d_in[8];
  const float* zw_b   = (const float*)d_in[9];
  const float* zb_h   = (const float*)d_in[10];
  const float* zb_x   = (const float*)d_in[11];
  const float* dw_h   = (const float*)d_in[12];
  const float* dw_x   = (const float*)d_in[13];
  const float* dw_b   = (const float*)d_in[14];
  const float* weight = (const float*)d_in[15];
  const float* bias   = (const float*)d_in[16];
  float* out = (float*)d_out;

  char* w = (char*)d_ws;
  auto take = [&](size_t bytes) { char* p = w; w += (bytes + 255) & ~(size_t)255; return p; };
  u16*   hcatb  = (u16*)take(2048ull * 2304 * 2);
  u16*   btc    = (u16*)take(5120ull * 2304 * 2);
  u16*   zwT    = (u16*)take(768ull * 256 * 2);
  u16*   dwT    = (u16*)take(12ull * 1024 * 64 * 2);
  u16*   grawb  = (u16*)take(2048ull * 4096 * 2);
  float* hgbuf  = (float*)take(2048ull * 1024 * 4);
  u16*   hhat1b = (u16*)take(2048ull * 256 * 2);
  u16*   zb16   = (u16*)take(2048ull * 768 * 2);

  float* h1_o    = out;
  float* c1_o    = out + 2048 * 1024;
  float* hhat1_o = out + 2 * 2048 * 1024;
  float* chat1_o = out + 2 * 2048 * 1024 + 2048 * 256;

  k_prep<<<4608 + 5760 + 480, 256, 0, stream>>>(
      hhat0, h0, x, weight, hweight, zw_h, zw_x, zw_b, dw_h, dw_x, dw_b,
      hcatb, btc, zwT, dwT);

  k_gemm_main<<<dim3(40, 16), 512, 0, stream>>>(hcatb, btc, hgbuf, grawb);

  k_hyper_act<<<2048, 256, 0, stream>>>(hgbuf, hbias, chat0, chat1_o, hhat1_o, hhat1b);

  k_gemm_z<<<dim3(6, 32), 256, 0, stream>>>(hhat1b, zwT, zb_h, zb_x, zb16);

  k_dmod_lstm<<<dim3(16, 64), 256, 0, stream>>>(zb16, dwT, grawb, bias, c0, h1_o, c1_o);
}